// Round 16
// baseline (195.137 us; speedup 1.0000x reference)
//
#include <hip/hip_runtime.h>
#include <math.h>

#define B_ 4
#define N_ 2048
#define H_ 128
#define K_ 32
#define L_ 4
#define OUT_ 6
#define BN_ (B_*N_)
#define NPB_L 16               // nodes per block
#define LBLK 512               // threads per block (8 waves)

typedef __attribute__((ext_vector_type(8))) short short8;
typedef __attribute__((ext_vector_type(4))) float f32x4;

#define LDW (H_ + 8)           // padded LDS row (bf16 elems)
#define LAYER_W 98304          // shorts/layer: w1a 16K | w1c 16K | w2 16K | u1 32K | u2 16K
#define OFF_W1A 0
#define OFF_W1C 16384
#define OFF_W2  32768
#define OFF_U1  49152
#define OFF_U2  81920
#define SCAP 256
#define KFBLK 512
#define KNN_ROWS 16                       // R16: 8->16, 2 rows/wave sequential
#define KNN_BLKS (BN_/KNN_ROWS)           // 512
#define PREP_BLKS (L_*LAYER_W/KFBLK)      // 768

#define LOG2E 1.44269504088896340736f
#define LN2   0.69314718055994530942f

// standard silu (u1 activation only; u1 weights NOT LOG2E-folded)
__device__ __forceinline__ float silu_f(float x) {
    float e = __builtin_amdgcn_exp2f(-x * LOG2E);
    return x * __builtin_amdgcn_rcpf(1.0f + e);
}
__device__ __forceinline__ short f2b(float f) {          // fp32 -> bf16 RNE
    unsigned u = __float_as_uint(f);
    return (short)((u + 0x7FFFu + ((u >> 16) & 1u)) >> 16);
}
__device__ __forceinline__ unsigned pack2(short lo, short hi) {
    return (unsigned)(unsigned short)lo | ((unsigned)(unsigned short)hi << 16);
}
__device__ __forceinline__ int mbcnt64(unsigned long long m) {
    return __builtin_amdgcn_mbcnt_hi((unsigned)(m >> 32),
           __builtin_amdgcn_mbcnt_lo((unsigned)m, 0));
}

// ---------------- k_front: knn | weight prep | E-prep ----------------
// R16: KNN_ROWS 16, each wave sequentially selects 2 rows (rr loop, not
// unrolled). Per-block staging (24KB x copy + barrier) amortizes over 2x
// rows -- the same work-halving mechanism that won in R14. Select/dist work
// and register pressure unchanged; per-wave skey/sid buffers reused across rr.
// Prep branch = R14 polarity (scattered reads, coalesced writes; R15's
// scattered-2B-writes variant regressed).
__global__ __launch_bounds__(KFBLK) void k_front(
    const float* __restrict__ x, int* __restrict__ nidx, float* __restrict__ ndist,
    const float* __restrict__ miw, const float* __restrict__ mow,
    const float* __restrict__ uiw, const float* __restrict__ uow,
    short* __restrict__ wt,
    const float* __restrict__ ew, const float* __restrict__ eb,
    const float* __restrict__ mib, float* __restrict__ Epack)
{
    __shared__ float xs[N_*3];                           // 24 KB linear
    __shared__ unsigned skey[8][SCAP];                   // 8 KB (per-wave)
    __shared__ int      sid [8][SCAP];                   // 8 KB (per-wave)

    if (blockIdx.x >= KNN_BLKS + PREP_BLKS) {
        // ---- E-prep: Ea = ew@W1a(l0), ea = eb@W1a + b1 ; Ec/ec likewise ----
        // Outputs pre-scaled by LOG2E. 256 active threads.
        int t = threadIdx.x;
        if (t >= 256) return;
        int which = t >> 7, n = t & 127;
        const float* W = miw + (size_t)(which ? 128 : 0) * H_;   // l=0 rows
        float E0 = 0.f, E1 = 0.f, E2 = 0.f, Eb = 0.f;
        for (int k = 0; k < 128; ++k) {
            float w = W[(size_t)k*H_ + n];
            E0 = fmaf(ew[k],       w, E0);
            E1 = fmaf(ew[128 + k], w, E1);
            E2 = fmaf(ew[256 + k], w, E2);
            Eb = fmaf(eb[k],       w, Eb);
        }
        float* dst = Epack + which * 512;    // [Ea(384)|ea(128)|Ec(384)|ec(128)]
        dst[0*128 + n] = E0 * LOG2E;
        dst[1*128 + n] = E1 * LOG2E;
        dst[2*128 + n] = E2 * LOG2E;
        dst[3*128 + n] = (Eb + (which ? 0.f : mib[n])) * LOG2E;
        return;
    }
    if (blockIdx.x >= KNN_BLKS) {
        // ---- prep: transpose+cast all layer weights to bf16 [n][k] ----
        // W1A/W1C regions pre-scaled by LOG2E. (R14 polarity: scattered
        // reads all in flight, coalesced 2B writes.)
        int gid = (blockIdx.x - KNN_BLKS) * KFBLK + threadIdx.x;
        int l = gid / LAYER_W, o = gid - l * LAYER_W;
        float v;
        if (o < OFF_W1C) {
            int n = o >> 7, k = o & 127;
            v = miw[(size_t)l*257*H_ + k*H_ + n] * LOG2E;
        } else if (o < OFF_W2) {
            int oo = o - OFF_W1C, n = oo >> 7, k = oo & 127;
            v = miw[(size_t)l*257*H_ + (128 + k)*H_ + n] * LOG2E;
        } else if (o < OFF_U1) {
            int oo = o - OFF_W2, n = oo >> 7, k = oo & 127;
            v = mow[(size_t)l*H_*H_ + k*H_ + n];
        } else if (o < OFF_U2) {
            int oo = o - OFF_U1, n = oo >> 8, k = oo & 255;
            v = uiw[(size_t)l*2*H_*H_ + k*H_ + n];
        } else {
            int oo = o - OFF_U2, n = oo >> 7, k = oo & 127;
            v = uow[(size_t)l*H_*H_ + k*H_ + n];
        }
        wt[gid] = f2b(v);
        return;
    }

    // ---- knn: 16 rows/block, 2 rows per wave (sequential) ----
    int b  = blockIdx.x / (N_/KNN_ROWS);
    int i0 = (blockIdx.x % (N_/KNN_ROWS)) * KNN_ROWS;
    const float* xb = x + (size_t)b*N_*3;
    for (int t = threadIdx.x; t < N_*3/4; t += KFBLK)   // 1536 float4, 3 iters
        ((float4*)xs)[t] = ((const float4*)xb)[t];
    __syncthreads();

    int wave = threadIdx.x >> 6, lane = threadIdx.x & 63;
    unsigned* sk = skey[wave];
    int*      si = sid [wave];

    for (int rr = 0; rr < 2; ++rr) {
        int i = i0 + wave*2 + rr;
        float xix = xs[3*i], xiy = xs[3*i+1], xiz = xs[3*i+2];

        unsigned u[N_/64];
        unsigned lmin = 0xFFFFFFFFu;
#pragma unroll
        for (int t = 0; t < N_/64; ++t) {
            int j = lane + 64*t;
            float d0 = xix-xs[3*j], d1 = xiy-xs[3*j+1], d2 = xiz-xs[3*j+2];
            float d = d0*d0 + d1*d1 + d2*d2;
            unsigned k = (j == i) ? 0x7F800000u : __float_as_uint(d);
            u[t] = k;
            lmin = min(lmin, k);
        }
        // wave min/max of lane minima -> common prefix (exact bit-search)
        unsigned mn = lmin, mx = lmin;
        for (int off = 32; off; off >>= 1) {
            unsigned o1 = (unsigned)__shfl_xor((int)mn, off); mn = min(mn, o1);
            unsigned o2 = (unsigned)__shfl_xor((int)mx, off); mx = max(mx, o2);
        }
        unsigned Tup = mn;
        if (mn != mx) {
            int hb = 31 - __clz((int)(mn ^ mx));
            Tup = mn & ~((2u << hb) - 1u);
            for (int bit = hb; bit >= 0; --bit) {
                unsigned cand = Tup | (1u << bit);
                if (__popcll(__ballot(lmin < cand)) < K_) Tup = cand;
            }
        }
        int base = 0;
#pragma unroll
        for (int t = 0; t < N_/64; ++t) {
            bool pr = (u[t] <= Tup);
            unsigned long long m = __ballot(pr);
            if (pr) {
                int pos = base + mbcnt64(m);
                if (pos < SCAP) { sk[pos] = u[t]; si[pos] = lane + 64*t; }
            }
            base += __popcll(m);
        }
        int c = min(base, SCAP);
        unsigned sv[4]; int iv[4];
#pragma unroll
        for (int q = 0; q < 4; ++q) {
            int slot = lane + 64*q;
            bool ok = slot < c;
            sv[q] = ok ? sk[slot] : 0xFFFFFFFFu;
            iv[q] = ok ? si[slot] : 0;
        }
        // exact K-th among survivors; answer in [mn, Tup]
        unsigned T = mn;
        if (mn != Tup) {
            int hb = 31 - __clz((int)(mn ^ Tup));
            T = mn & ~((2u << hb) - 1u);
            for (int bit = hb; bit >= 0; --bit) {
                unsigned cand = T | (1u << bit);
                int cnt = __popcll(__ballot(sv[0] < cand)) + __popcll(__ballot(sv[1] < cand))
                        + __popcll(__ballot(sv[2] < cand)) + __popcll(__ballot(sv[3] < cand));
                if (cnt < K_) T = cand;
            }
        }
        int cnt_lt = __popcll(__ballot(sv[0] < T)) + __popcll(__ballot(sv[1] < T))
                   + __popcll(__ballot(sv[2] < T)) + __popcll(__ballot(sv[3] < T));
        int need = K_ - cnt_lt;
        size_t rbase = ((size_t)(b*N_ + i)) * K_;
        int ltc = 0, eqc = 0;
#pragma unroll
        for (int q = 0; q < 4; ++q) {
            bool lt = sv[q] < T, eq = sv[q] == T;
            unsigned long long mlt = __ballot(lt), meq = __ballot(eq);
            int pp = ltc + mbcnt64(mlt), ee = eqc + mbcnt64(meq);
            ltc += __popcll(mlt); eqc += __popcll(meq);
            int pos = lt ? pp : ((eq && ee < need) ? (cnt_lt + ee) : -1);
            if (pos >= 0) {
                nidx [rbase + pos] = iv[q];
                ndist[rbase + pos] = sqrtf(__uint_as_float(sv[q]));
            }
        }
    }
}

// ---------------- k_prep0: per-node h0 / a(0) / c(0) via E-fusion ----------------
__global__ __launch_bounds__(512) void k_prep0(
    float* __restrict__ h, short* __restrict__ a, short* __restrict__ c0,
    const float* __restrict__ x, const float* __restrict__ ew,
    const float* __restrict__ eb, const float* __restrict__ Epack)
{
    int t = blockIdx.x * 512 + threadIdx.x;   // (node, ch): BN*H threads
    int node = t >> 7, ch = t & 127;
    const float* xp = x + (size_t)node*3;
    float x0 = xp[0], x1 = xp[1], x2 = xp[2];
    float hv = eb[ch];
    hv = fmaf(x0, ew[ch],       hv);
    hv = fmaf(x1, ew[H_+ch],    hv);
    hv = fmaf(x2, ew[2*H_+ch],  hv);
    float av = Epack[384+ch];
    av = fmaf(x0, Epack[ch],     av);
    av = fmaf(x1, Epack[128+ch], av);
    av = fmaf(x2, Epack[256+ch], av);
    float cv = Epack[896+ch];
    cv = fmaf(x0, Epack[512+ch], cv);
    cv = fmaf(x1, Epack[640+ch], cv);
    cv = fmaf(x2, Epack[768+ch], cv);
    size_t gi = (size_t)node*H_ + ch;
    h[gi]  = hv;
    a[gi]  = f2b(av);
    c0[gi] = f2b(cv);
}

// ---------------- k_layer (uniform, l = 0..3): R9 body; skip h store on l=3 ----------------
__global__ __launch_bounds__(LBLK, 4) void k_layer(
    float* __restrict__ h, short* __restrict__ a,
    const int* __restrict__ nidx, const float* __restrict__ ndist,
    const float* __restrict__ wd,
    const short* __restrict__ wl,
    const float* __restrict__ b2, const float* __restrict__ u1b,
    const float* __restrict__ u2b,
    const short* __restrict__ c_rd, short* __restrict__ c_wr,
    const short* __restrict__ wn, const float* __restrict__ b1n, int do_ac,
    const float* __restrict__ ow, const float* __restrict__ ob,
    float* __restrict__ out)
{
    __shared__ __align__(16) short s_l[NPB_L][LDW];
    __shared__ __align__(16) short h_l[NPB_L][LDW];
    __shared__ __align__(16) short agg_l[NPB_L][LDW];
    __shared__ __align__(16) float h32s[NPB_L][H_];
    __shared__ int   idx_s[NPB_L][K_];
    __shared__ float dst_s[NPB_L][K_];
    int blk = blockIdx.x;
    int batch = (blk & 7) >> 1;
    int sub   = ((blk >> 3) << 1) | (blk & 1);
    int node0 = batch * N_ + sub * NPB_L;
    int tid = threadIdx.x;
    int wave = tid >> 6, lane = tid & 63, l15 = lane & 15, quad = lane >> 4;
    int ncol = wave*16 + l15;

    {
        float4 v = reinterpret_cast<const float4*>(h + (size_t)node0*H_)[tid];
        int row = tid >> 5, col = (tid & 31) * 4;
        h_l[row][col+0] = f2b(v.x); h_l[row][col+1] = f2b(v.y);
        h_l[row][col+2] = f2b(v.z); h_l[row][col+3] = f2b(v.w);
        *(float4*)&h32s[row][col] = v;
    }
    idx_s[tid>>5][tid&31] = nidx[(size_t)node0*K_ + tid];
    dst_s[tid>>5][tid&31] = ndist[(size_t)node0*K_ + tid];
    __syncthreads();

    // ---- edge: real loops, 8-deep gather chunks ----
    {
        float wd0 = wd[2*lane] * LOG2E, wd1 = wd[2*lane+1] * LOG2E;
        int wavu = __builtin_amdgcn_readfirstlane(wave);
        const unsigned* c2 = (const unsigned*)c_rd + (size_t)batch*N_*(H_/2);
        const unsigned* a2 = (const unsigned*)a;
        for (int nn = 0; nn < 2; ++nn) {
            int m = wavu*2 + nn;
            unsigned av = a2[(size_t)(node0+m)*(H_/2) + lane];
            float a0 = __uint_as_float(av << 16);
            float a1 = __uint_as_float(av & 0xFFFF0000u);
            float s0 = 0.f, s1 = 0.f;
            for (int kc = 0; kc < K_; kc += 8) {
                unsigned cv[8];
#pragma unroll
                for (int k = 0; k < 8; ++k) {
                    int j = __builtin_amdgcn_readfirstlane(idx_s[m][kc + k]);
                    cv[k] = c2[(size_t)j*(H_/2) + lane];
                }
#pragma unroll
                for (int k = 0; k < 8; ++k) {
                    float dd = dst_s[m][kc + k];
                    float y0 = a0 + fmaf(dd, wd0, __uint_as_float(cv[k] << 16));
                    float y1 = a1 + fmaf(dd, wd1, __uint_as_float(cv[k] & 0xFFFF0000u));
                    float t0 = __builtin_amdgcn_rcpf(1.0f + __builtin_amdgcn_exp2f(-y0));
                    float t1 = __builtin_amdgcn_rcpf(1.0f + __builtin_amdgcn_exp2f(-y1));
                    s0 = fmaf(y0, t0, s0);
                    s1 = fmaf(y1, t1, s1);
                }
            }
            *(unsigned*)&s_l[m][2*lane] = pack2(f2b(s0 * LN2), f2b(s1 * LN2));
        }
    }
    __syncthreads();

    f32x4 acc;
    // ---- GEMM1 (weights at use) ----
    acc = (f32x4){0,0,0,0};
#pragma unroll
    for (int kk = 0; kk < 4; ++kk) {
        int k0 = kk*32 + quad*8;
        short8 bf = *(const short8*)(wl + OFF_W2 + (size_t)ncol*H_ + k0);
        short8 af = *(const short8*)&s_l[l15][k0];
        acc = __builtin_amdgcn_mfma_f32_16x16x32_bf16(af, bf, acc, 0, 0, 0);
    }
    {
        float b2v = b2[ncol] * (float)K_;
#pragma unroll
        for (int r = 0; r < 4; ++r)
            agg_l[quad*4 + r][ncol] = f2b(acc[r] + b2v);
    }
    __syncthreads();

    // ---- GEMM2 ----
    acc = (f32x4){0,0,0,0};
#pragma unroll
    for (int kk = 0; kk < 8; ++kk) {
        const short (*src)[LDW] = (kk < 4) ? h_l : agg_l;
        int kloc = ((kk < 4) ? kk*32 : (kk-4)*32) + quad*8;
        short8 bf = *(const short8*)(wl + OFF_U1 + (size_t)ncol*2*H_ + kk*32 + quad*8);
        short8 af = *(const short8*)&src[l15][kloc];
        acc = __builtin_amdgcn_mfma_f32_16x16x32_bf16(af, bf, acc, 0, 0, 0);
    }
    {
        float u1bv = u1b[ncol];
#pragma unroll
        for (int r = 0; r < 4; ++r)
            s_l[quad*4 + r][ncol] = f2b(silu_f(acc[r] + u1bv));
    }
    __syncthreads();

    // ---- GEMM3 + residual ----
    acc = (f32x4){0,0,0,0};
#pragma unroll
    for (int kk = 0; kk < 4; ++kk) {
        int k0 = kk*32 + quad*8;
        short8 bf = *(const short8*)(wl + OFF_U2 + (size_t)ncol*H_ + k0);
        short8 af = *(const short8*)&s_l[l15][k0];
        acc = __builtin_amdgcn_mfma_f32_16x16x32_bf16(af, bf, acc, 0, 0, 0);
    }
    {
        float u2bv = u2b[ncol];
#pragma unroll
        for (int r = 0; r < 4; ++r) {
            int m = quad*4 + r;
            float nh = h32s[m][ncol] + acc[r] + u2bv;
            if (do_ac) {
                h[(size_t)(node0+m)*H_ + ncol] = nh;   // next layer reads h
                h_l[m][ncol] = f2b(nh);
            } else {
                h32s[m][ncol] = nh;                    // l=3: out-proj only
            }
        }
    }
    if (do_ac) {
        __syncthreads();
        int n = ncol;
        f32x4 accA = (f32x4){0,0,0,0}, accC = (f32x4){0,0,0,0};
#pragma unroll
        for (int kk = 0; kk < 4; ++kk) {
            int k0 = kk*32 + quad*8;
            short8 af = *(const short8*)&h_l[l15][k0];
            short8 bA = *(const short8*)(wn + OFF_W1A + (size_t)ncol*H_ + k0);
            short8 bC = *(const short8*)(wn + OFF_W1C + (size_t)ncol*H_ + k0);
            accA = __builtin_amdgcn_mfma_f32_16x16x32_bf16(af, bA, accA, 0, 0, 0);
            accC = __builtin_amdgcn_mfma_f32_16x16x32_bf16(af, bC, accC, 0, 0, 0);
        }
        float b1v = b1n[n] * LOG2E;
#pragma unroll
        for (int r = 0; r < 4; ++r) {
            int m = quad*4 + r;
            size_t gi = (size_t)(node0+m)*H_ + n;
            a[gi]    = f2b(accA[r] + b1v);
            c_wr[gi] = f2b(accC[r]);
        }
    } else {
        __syncthreads();
        // parallel out-proj: 32 lanes per node, 4 h-elems each, shuffle-reduce
        int node = tid >> 5, s = tid & 31;
        float p0=0.f,p1=0.f,p2=0.f,p3=0.f,p4=0.f,p5=0.f;
#pragma unroll
        for (int q = 0; q < 4; ++q) {
            int r = s + q*32;
            float hv = h32s[node][r];
            const float* owr = ow + r*OUT_;
            p0 = fmaf(hv, owr[0], p0); p1 = fmaf(hv, owr[1], p1);
            p2 = fmaf(hv, owr[2], p2); p3 = fmaf(hv, owr[3], p3);
            p4 = fmaf(hv, owr[4], p4); p5 = fmaf(hv, owr[5], p5);
        }
#pragma unroll
        for (int off = 16; off; off >>= 1) {
            p0 += __shfl_xor(p0, off); p1 += __shfl_xor(p1, off);
            p2 += __shfl_xor(p2, off); p3 += __shfl_xor(p3, off);
            p4 += __shfl_xor(p4, off); p5 += __shfl_xor(p5, off);
        }
        if (s == 0) {
            float* op = out + (size_t)(node0+node)*OUT_;
            op[0] = p0 + ob[0]; op[1] = p1 + ob[1]; op[2] = p2 + ob[2];
            op[3] = p3 + ob[3]; op[4] = p4 + ob[4]; op[5] = p5 + ob[5];
        }
    }
}

extern "C" void kernel_launch(void* const* d_in, const int* in_sizes, int n_in,
                              void* d_out, int out_size, void* d_ws, size_t ws_size,
                              hipStream_t stream)
{
    const float* x   = (const float*)d_in[0];
    const float* ew  = (const float*)d_in[1];
    const float* eb  = (const float*)d_in[2];
    const float* miw = (const float*)d_in[3];
    const float* mib = (const float*)d_in[4];
    const float* mow = (const float*)d_in[5];
    const float* mob = (const float*)d_in[6];
    const float* uiw = (const float*)d_in[7];
    const float* uib = (const float*)d_in[8];
    const float* uow = (const float*)d_in[9];
    const float* uob = (const float*)d_in[10];
    const float* ow  = (const float*)d_in[11];
    const float* ob  = (const float*)d_in[12];
    float* out = (float*)d_out;

    // workspace: h fp32 | nd fp32 | ni i32 | a bf16 | c0 bf16 | c1 bf16 | wt bf16 | Epack fp32
    char* w = (char*)d_ws;
    float* h  = (float*)w;                         w += (size_t)BN_*H_*4;
    float* nd = (float*)w;                         w += (size_t)BN_*K_*4;
    int*   ni = (int*)w;                           w += (size_t)BN_*K_*4;
    short* a  = (short*)w;                         w += (size_t)BN_*H_*2;
    short* c0 = (short*)w;                         w += (size_t)BN_*H_*2;
    short* c1 = (short*)w;                         w += (size_t)BN_*H_*2;
    short* wt = (short*)w;                         w += (size_t)L_*LAYER_W*2;
    float* Epack = (float*)w;                                               // 4 KB

    k_front<<<KNN_BLKS + PREP_BLKS + 1, KFBLK, 0, stream>>>(x, ni, nd,
        miw, mow, uiw, uow, wt, ew, eb, mib, Epack);
    // per-node h0 / a(0) / c(0) via E-fusion
    k_prep0<<<BN_*H_/512, 512, 0, stream>>>(h, a, c0, x, ew, eb, Epack);
    // uniform layer loop, l = 0..3
    for (int l = 0; l < L_; ++l) {
        const short* c_rd = (l & 1) ? c1 : c0;
        short*       c_wr = (l & 1) ? c0 : c1;
        int do_ac = (l + 1 < L_);
        const short* wn = wt + (size_t)(do_ac ? (l+1) : l) * LAYER_W;
        const float* b1n = mib + (size_t)(do_ac ? (l+1) : l) * H_;
        k_layer<<<BN_/NPB_L, LBLK, 0, stream>>>(h, a, ni, nd,
            miw + (size_t)l*257*H_ + 256*H_,
            wt + (size_t)l*LAYER_W,
            mob + (size_t)l*H_, uib + (size_t)l*H_, uob + (size_t)l*H_,
            c_rd, c_wr, wn, b1n, do_ac,
            ow, ob, out);
    }
}

// Round 18
// 191.152 us; speedup vs baseline: 1.0208x; 1.0208x over previous
//
#include <hip/hip_runtime.h>
#include <math.h>

#define B_ 4
#define N_ 2048
#define H_ 128
#define K_ 32
#define L_ 4
#define OUT_ 6
#define BN_ (B_*N_)
#define NPB_L 16               // nodes per block
#define LBLK 512               // threads per block (8 waves)

typedef __attribute__((ext_vector_type(8))) short short8;
typedef __attribute__((ext_vector_type(4))) float f32x4;

#define LDW (H_ + 8)           // padded LDS row (bf16 elems)
#define LAYER_W 98304          // shorts/layer: w1a 16K | w1c 16K | w2 16K | u1 32K | u2 16K
#define OFF_W1A 0
#define OFF_W1C 16384
#define OFF_W2  32768
#define OFF_U1  49152
#define OFF_U2  81920
#define SCAP 256
#define KFBLK 512
#define KNN_ROWS 8                        // R14 best config
#define KNN_BLKS (BN_/KNN_ROWS)           // 1024
#define PREP_BLKS (L_*LAYER_W/KFBLK)      // 768

#define LOG2E 1.44269504088896340736f
#define LN2   0.69314718055994530942f

// standard silu (u1 activation only; u1 weights NOT LOG2E-folded)
__device__ __forceinline__ float silu_f(float x) {
    float e = __builtin_amdgcn_exp2f(-x * LOG2E);
    return x * __builtin_amdgcn_rcpf(1.0f + e);
}
__device__ __forceinline__ short f2b(float f) {          // fp32 -> bf16 RNE
    unsigned u = __float_as_uint(f);
    return (short)((u + 0x7FFFu + ((u >> 16) & 1u)) >> 16);
}
__device__ __forceinline__ unsigned pack2(short lo, short hi) {
    return (unsigned)(unsigned short)lo | ((unsigned)(unsigned short)hi << 16);
}
__device__ __forceinline__ int mbcnt64(unsigned long long m) {
    return __builtin_amdgcn_mbcnt_hi((unsigned)(m >> 32),
           __builtin_amdgcn_mbcnt_lo((unsigned)m, 0));
}

// ---------------- k_front: knn | weight prep | E-prep ----------------
// R14 best: 8 rows/block @ 512 thr; staging = linear float4 copy (no
// div/mod-by-3, no 3-way LDS scatter); dist reads xs[3j+r]: stride 3 coprime
// with 32 banks -> conflict-free.
__global__ __launch_bounds__(KFBLK) void k_front(
    const float* __restrict__ x, int* __restrict__ nidx, float* __restrict__ ndist,
    const float* __restrict__ miw, const float* __restrict__ mow,
    const float* __restrict__ uiw, const float* __restrict__ uow,
    short* __restrict__ wt,
    const float* __restrict__ ew, const float* __restrict__ eb,
    const float* __restrict__ mib, float* __restrict__ Epack)
{
    __shared__ float xs[N_*3];                           // 24 KB linear
    __shared__ unsigned skey[KNN_ROWS][SCAP];            // 8 KB
    __shared__ int      sid [KNN_ROWS][SCAP];            // 8 KB

    if (blockIdx.x >= KNN_BLKS + PREP_BLKS) {
        // ---- E-prep: Ea = ew@W1a(l0), ea = eb@W1a + b1 ; Ec/ec likewise ----
        // Outputs pre-scaled by LOG2E. 256 active threads.
        int t = threadIdx.x;
        if (t >= 256) return;
        int which = t >> 7, n = t & 127;
        const float* W = miw + (size_t)(which ? 128 : 0) * H_;   // l=0 rows
        float E0 = 0.f, E1 = 0.f, E2 = 0.f, Eb = 0.f;
        for (int k = 0; k < 128; ++k) {
            float w = W[(size_t)k*H_ + n];
            E0 = fmaf(ew[k],       w, E0);
            E1 = fmaf(ew[128 + k], w, E1);
            E2 = fmaf(ew[256 + k], w, E2);
            Eb = fmaf(eb[k],       w, Eb);
        }
        float* dst = Epack + which * 512;    // [Ea(384)|ea(128)|Ec(384)|ec(128)]
        dst[0*128 + n] = E0 * LOG2E;
        dst[1*128 + n] = E1 * LOG2E;
        dst[2*128 + n] = E2 * LOG2E;
        dst[3*128 + n] = (Eb + (which ? 0.f : mib[n])) * LOG2E;
        return;
    }
    if (blockIdx.x >= KNN_BLKS) {
        // ---- prep: transpose+cast all layer weights to bf16 [n][k] ----
        // W1A/W1C regions pre-scaled by LOG2E.
        int gid = (blockIdx.x - KNN_BLKS) * KFBLK + threadIdx.x;
        int l = gid / LAYER_W, o = gid - l * LAYER_W;
        float v;
        if (o < OFF_W1C) {
            int n = o >> 7, k = o & 127;
            v = miw[(size_t)l*257*H_ + k*H_ + n] * LOG2E;
        } else if (o < OFF_W2) {
            int oo = o - OFF_W1C, n = oo >> 7, k = oo & 127;
            v = miw[(size_t)l*257*H_ + (128 + k)*H_ + n] * LOG2E;
        } else if (o < OFF_U1) {
            int oo = o - OFF_W2, n = oo >> 7, k = oo & 127;
            v = mow[(size_t)l*H_*H_ + k*H_ + n];
        } else if (o < OFF_U2) {
            int oo = o - OFF_U1, n = oo >> 8, k = oo & 255;
            v = uiw[(size_t)l*2*H_*H_ + k*H_ + n];
        } else {
            int oo = o - OFF_U2, n = oo >> 7, k = oo & 127;
            v = uow[(size_t)l*H_*H_ + k*H_ + n];
        }
        wt[gid] = f2b(v);
        return;
    }

    // ---- knn: 8 rows/block, ballot select of K smallest d^2 per row ----
    int b  = blockIdx.x / (N_/KNN_ROWS);
    int i0 = (blockIdx.x % (N_/KNN_ROWS)) * KNN_ROWS;
    const float* xb = x + (size_t)b*N_*3;
    for (int t = threadIdx.x; t < N_*3/4; t += KFBLK)   // 1536 float4, 3 iters
        ((float4*)xs)[t] = ((const float4*)xb)[t];
    __syncthreads();

    int wave = threadIdx.x >> 6, lane = threadIdx.x & 63;
    int i = i0 + wave;
    float xix = xs[3*i], xiy = xs[3*i+1], xiz = xs[3*i+2];

    unsigned u[N_/64];
    unsigned lmin = 0xFFFFFFFFu;
#pragma unroll
    for (int t = 0; t < N_/64; ++t) {
        int j = lane + 64*t;
        float d0 = xix-xs[3*j], d1 = xiy-xs[3*j+1], d2 = xiz-xs[3*j+2];
        float d = d0*d0 + d1*d1 + d2*d2;
        unsigned k = (j == i) ? 0x7F800000u : __float_as_uint(d);
        u[t] = k;
        lmin = min(lmin, k);
    }
    // wave min/max of lane minima -> common prefix (exact bit-search narrowing)
    unsigned mn = lmin, mx = lmin;
    for (int off = 32; off; off >>= 1) {
        unsigned o1 = (unsigned)__shfl_xor((int)mn, off); mn = min(mn, o1);
        unsigned o2 = (unsigned)__shfl_xor((int)mx, off); mx = max(mx, o2);
    }
    unsigned Tup = mn;
    if (mn != mx) {
        int hb = 31 - __clz((int)(mn ^ mx));
        Tup = mn & ~((2u << hb) - 1u);
        for (int bit = hb; bit >= 0; --bit) {
            unsigned cand = Tup | (1u << bit);
            if (__popcll(__ballot(lmin < cand)) < K_) Tup = cand;
        }
    }
    unsigned* sk = skey[wave];
    int*      si = sid [wave];
    int base = 0;
#pragma unroll
    for (int t = 0; t < N_/64; ++t) {
        bool pr = (u[t] <= Tup);
        unsigned long long m = __ballot(pr);
        if (pr) {
            int pos = base + mbcnt64(m);
            if (pos < SCAP) { sk[pos] = u[t]; si[pos] = lane + 64*t; }
        }
        base += __popcll(m);
    }
    int c = min(base, SCAP);
    unsigned sv[4]; int iv[4];
#pragma unroll
    for (int q = 0; q < 4; ++q) {
        int slot = lane + 64*q;
        bool ok = slot < c;
        sv[q] = ok ? sk[slot] : 0xFFFFFFFFu;
        iv[q] = ok ? si[slot] : 0;
    }
    // exact K-th among survivors; answer in [mn, Tup] -> narrowed search
    unsigned T = mn;
    if (mn != Tup) {
        int hb = 31 - __clz((int)(mn ^ Tup));
        T = mn & ~((2u << hb) - 1u);
        for (int bit = hb; bit >= 0; --bit) {
            unsigned cand = T | (1u << bit);
            int cnt = __popcll(__ballot(sv[0] < cand)) + __popcll(__ballot(sv[1] < cand))
                    + __popcll(__ballot(sv[2] < cand)) + __popcll(__ballot(sv[3] < cand));
            if (cnt < K_) T = cand;
        }
    }
    int cnt_lt = __popcll(__ballot(sv[0] < T)) + __popcll(__ballot(sv[1] < T))
               + __popcll(__ballot(sv[2] < T)) + __popcll(__ballot(sv[3] < T));
    int need = K_ - cnt_lt;
    size_t rbase = ((size_t)(b*N_ + i)) * K_;
    int ltc = 0, eqc = 0;
#pragma unroll
    for (int q = 0; q < 4; ++q) {
        bool lt = sv[q] < T, eq = sv[q] == T;
        unsigned long long mlt = __ballot(lt), meq = __ballot(eq);
        int pp = ltc + mbcnt64(mlt), ee = eqc + mbcnt64(meq);
        ltc += __popcll(mlt); eqc += __popcll(meq);
        int pos = lt ? pp : ((eq && ee < need) ? (cnt_lt + ee) : -1);
        if (pos >= 0) {
            nidx [rbase + pos] = iv[q];
            ndist[rbase + pos] = sqrtf(__uint_as_float(sv[q]));
        }
    }
}

// ---------------- k_prep0: per-node h0 / a(0) / c(0) via E-fusion ----------------
__global__ __launch_bounds__(512) void k_prep0(
    float* __restrict__ h, short* __restrict__ a, short* __restrict__ c0,
    const float* __restrict__ x, const float* __restrict__ ew,
    const float* __restrict__ eb, const float* __restrict__ Epack)
{
    int t = blockIdx.x * 512 + threadIdx.x;   // (node, ch): BN*H threads
    int node = t >> 7, ch = t & 127;
    const float* xp = x + (size_t)node*3;
    float x0 = xp[0], x1 = xp[1], x2 = xp[2];
    float hv = eb[ch];
    hv = fmaf(x0, ew[ch],       hv);
    hv = fmaf(x1, ew[H_+ch],    hv);
    hv = fmaf(x2, ew[2*H_+ch],  hv);
    float av = Epack[384+ch];
    av = fmaf(x0, Epack[ch],     av);
    av = fmaf(x1, Epack[128+ch], av);
    av = fmaf(x2, Epack[256+ch], av);
    float cv = Epack[896+ch];
    cv = fmaf(x0, Epack[512+ch], cv);
    cv = fmaf(x1, Epack[640+ch], cv);
    cv = fmaf(x2, Epack[768+ch], cv);
    size_t gi = (size_t)node*H_ + ch;
    h[gi]  = hv;
    a[gi]  = f2b(av);
    c0[gi] = f2b(cv);
}

// ---------------- k_layer (uniform, l = 0..3): R9 code-diet body ----------------
__global__ __launch_bounds__(LBLK, 4) void k_layer(
    float* __restrict__ h, short* __restrict__ a,
    const int* __restrict__ nidx, const float* __restrict__ ndist,
    const float* __restrict__ wd,
    const short* __restrict__ wl,
    const float* __restrict__ b2, const float* __restrict__ u1b,
    const float* __restrict__ u2b,
    const short* __restrict__ c_rd, short* __restrict__ c_wr,
    const short* __restrict__ wn, const float* __restrict__ b1n, int do_ac,
    const float* __restrict__ ow, const float* __restrict__ ob,
    float* __restrict__ out)
{
    __shared__ __align__(16) short s_l[NPB_L][LDW];
    __shared__ __align__(16) short h_l[NPB_L][LDW];
    __shared__ __align__(16) short agg_l[NPB_L][LDW];
    __shared__ __align__(16) float h32s[NPB_L][H_];
    __shared__ int   idx_s[NPB_L][K_];
    __shared__ float dst_s[NPB_L][K_];
    int blk = blockIdx.x;
    int batch = (blk & 7) >> 1;
    int sub   = ((blk >> 3) << 1) | (blk & 1);
    int node0 = batch * N_ + sub * NPB_L;
    int tid = threadIdx.x;
    int wave = tid >> 6, lane = tid & 63, l15 = lane & 15, quad = lane >> 4;
    int ncol = wave*16 + l15;

    {
        float4 v = reinterpret_cast<const float4*>(h + (size_t)node0*H_)[tid];
        int row = tid >> 5, col = (tid & 31) * 4;
        h_l[row][col+0] = f2b(v.x); h_l[row][col+1] = f2b(v.y);
        h_l[row][col+2] = f2b(v.z); h_l[row][col+3] = f2b(v.w);
        *(float4*)&h32s[row][col] = v;
    }
    idx_s[tid>>5][tid&31] = nidx[(size_t)node0*K_ + tid];
    dst_s[tid>>5][tid&31] = ndist[(size_t)node0*K_ + tid];
    __syncthreads();

    // ---- edge: real loops, 8-deep gather chunks ----
    {
        float wd0 = wd[2*lane] * LOG2E, wd1 = wd[2*lane+1] * LOG2E;
        int wavu = __builtin_amdgcn_readfirstlane(wave);
        const unsigned* c2 = (const unsigned*)c_rd + (size_t)batch*N_*(H_/2);
        const unsigned* a2 = (const unsigned*)a;
        for (int nn = 0; nn < 2; ++nn) {
            int m = wavu*2 + nn;
            unsigned av = a2[(size_t)(node0+m)*(H_/2) + lane];
            float a0 = __uint_as_float(av << 16);
            float a1 = __uint_as_float(av & 0xFFFF0000u);
            float s0 = 0.f, s1 = 0.f;
            for (int kc = 0; kc < K_; kc += 8) {
                unsigned cv[8];
#pragma unroll
                for (int k = 0; k < 8; ++k) {
                    int j = __builtin_amdgcn_readfirstlane(idx_s[m][kc + k]);
                    cv[k] = c2[(size_t)j*(H_/2) + lane];
                }
#pragma unroll
                for (int k = 0; k < 8; ++k) {
                    float dd = dst_s[m][kc + k];
                    float y0 = a0 + fmaf(dd, wd0, __uint_as_float(cv[k] << 16));
                    float y1 = a1 + fmaf(dd, wd1, __uint_as_float(cv[k] & 0xFFFF0000u));
                    float t0 = __builtin_amdgcn_rcpf(1.0f + __builtin_amdgcn_exp2f(-y0));
                    float t1 = __builtin_amdgcn_rcpf(1.0f + __builtin_amdgcn_exp2f(-y1));
                    s0 = fmaf(y0, t0, s0);
                    s1 = fmaf(y1, t1, s1);
                }
            }
            *(unsigned*)&s_l[m][2*lane] = pack2(f2b(s0 * LN2), f2b(s1 * LN2));
        }
    }
    __syncthreads();

    f32x4 acc;
    // ---- GEMM1 (weights at use) ----
    acc = (f32x4){0,0,0,0};
#pragma unroll
    for (int kk = 0; kk < 4; ++kk) {
        int k0 = kk*32 + quad*8;
        short8 bf = *(const short8*)(wl + OFF_W2 + (size_t)ncol*H_ + k0);
        short8 af = *(const short8*)&s_l[l15][k0];
        acc = __builtin_amdgcn_mfma_f32_16x16x32_bf16(af, bf, acc, 0, 0, 0);
    }
    {
        float b2v = b2[ncol] * (float)K_;
#pragma unroll
        for (int r = 0; r < 4; ++r)
            agg_l[quad*4 + r][ncol] = f2b(acc[r] + b2v);
    }
    __syncthreads();

    // ---- GEMM2 ----
    acc = (f32x4){0,0,0,0};
#pragma unroll
    for (int kk = 0; kk < 8; ++kk) {
        const short (*src)[LDW] = (kk < 4) ? h_l : agg_l;
        int kloc = ((kk < 4) ? kk*32 : (kk-4)*32) + quad*8;
        short8 bf = *(const short8*)(wl + OFF_U1 + (size_t)ncol*2*H_ + kk*32 + quad*8);
        short8 af = *(const short8*)&src[l15][kloc];
        acc = __builtin_amdgcn_mfma_f32_16x16x32_bf16(af, bf, acc, 0, 0, 0);
    }
    {
        float u1bv = u1b[ncol];
#pragma unroll
        for (int r = 0; r < 4; ++r)
            s_l[quad*4 + r][ncol] = f2b(silu_f(acc[r] + u1bv));
    }
    __syncthreads();

    // ---- GEMM3 + residual ----
    acc = (f32x4){0,0,0,0};
#pragma unroll
    for (int kk = 0; kk < 4; ++kk) {
        int k0 = kk*32 + quad*8;
        short8 bf = *(const short8*)(wl + OFF_U2 + (size_t)ncol*H_ + k0);
        short8 af = *(const short8*)&s_l[l15][k0];
        acc = __builtin_amdgcn_mfma_f32_16x16x32_bf16(af, bf, acc, 0, 0, 0);
    }
    {
        float u2bv = u2b[ncol];
#pragma unroll
        for (int r = 0; r < 4; ++r) {
            int m = quad*4 + r;
            float nh = h32s[m][ncol] + acc[r] + u2bv;
            h[(size_t)(node0+m)*H_ + ncol] = nh;
            if (do_ac) h_l[m][ncol] = f2b(nh);
            else       h32s[m][ncol] = nh;
        }
    }
    if (do_ac) {
        __syncthreads();
        int n = ncol;
        f32x4 accA = (f32x4){0,0,0,0}, accC = (f32x4){0,0,0,0};
#pragma unroll
        for (int kk = 0; kk < 4; ++kk) {
            int k0 = kk*32 + quad*8;
            short8 af = *(const short8*)&h_l[l15][k0];
            short8 bA = *(const short8*)(wn + OFF_W1A + (size_t)ncol*H_ + k0);
            short8 bC = *(const short8*)(wn + OFF_W1C + (size_t)ncol*H_ + k0);
            accA = __builtin_amdgcn_mfma_f32_16x16x32_bf16(af, bA, accA, 0, 0, 0);
            accC = __builtin_amdgcn_mfma_f32_16x16x32_bf16(af, bC, accC, 0, 0, 0);
        }
        float b1v = b1n[n] * LOG2E;
#pragma unroll
        for (int r = 0; r < 4; ++r) {
            int m = quad*4 + r;
            size_t gi = (size_t)(node0+m)*H_ + n;
            a[gi]    = f2b(accA[r] + b1v);
            c_wr[gi] = f2b(accC[r]);
        }
    } else {
        __syncthreads();
        // parallel out-proj: 32 lanes per node, 4 h-elems each, shuffle-reduce
        int node = tid >> 5, s = tid & 31;
        float p0=0.f,p1=0.f,p2=0.f,p3=0.f,p4=0.f,p5=0.f;
#pragma unroll
        for (int q = 0; q < 4; ++q) {
            int r = s + q*32;
            float hv = h32s[node][r];
            const float* owr = ow + r*OUT_;
            p0 = fmaf(hv, owr[0], p0); p1 = fmaf(hv, owr[1], p1);
            p2 = fmaf(hv, owr[2], p2); p3 = fmaf(hv, owr[3], p3);
            p4 = fmaf(hv, owr[4], p4); p5 = fmaf(hv, owr[5], p5);
        }
#pragma unroll
        for (int off = 16; off; off >>= 1) {
            p0 += __shfl_xor(p0, off); p1 += __shfl_xor(p1, off);
            p2 += __shfl_xor(p2, off); p3 += __shfl_xor(p3, off);
            p4 += __shfl_xor(p4, off); p5 += __shfl_xor(p5, off);
        }
        if (s == 0) {
            float* op = out + (size_t)(node0+node)*OUT_;
            op[0] = p0 + ob[0]; op[1] = p1 + ob[1]; op[2] = p2 + ob[2];
            op[3] = p3 + ob[3]; op[4] = p4 + ob[4]; op[5] = p5 + ob[5];
        }
    }
}

extern "C" void kernel_launch(void* const* d_in, const int* in_sizes, int n_in,
                              void* d_out, int out_size, void* d_ws, size_t ws_size,
                              hipStream_t stream)
{
    const float* x   = (const float*)d_in[0];
    const float* ew  = (const float*)d_in[1];
    const float* eb  = (const float*)d_in[2];
    const float* miw = (const float*)d_in[3];
    const float* mib = (const float*)d_in[4];
    const float* mow = (const float*)d_in[5];
    const float* mob = (const float*)d_in[6];
    const float* uiw = (const float*)d_in[7];
    const float* uib = (const float*)d_in[8];
    const float* uow = (const float*)d_in[9];
    const float* uob = (const float*)d_in[10];
    const float* ow  = (const float*)d_in[11];
    const float* ob  = (const float*)d_in[12];
    float* out = (float*)d_out;

    // workspace: h fp32 | nd fp32 | ni i32 | a bf16 | c0 bf16 | c1 bf16 | wt bf16 | Epack fp32
    char* w = (char*)d_ws;
    float* h  = (float*)w;                         w += (size_t)BN_*H_*4;
    float* nd = (float*)w;                         w += (size_t)BN_*K_*4;
    int*   ni = (int*)w;                           w += (size_t)BN_*K_*4;
    short* a  = (short*)w;                         w += (size_t)BN_*H_*2;
    short* c0 = (short*)w;                         w += (size_t)BN_*H_*2;
    short* c1 = (short*)w;                         w += (size_t)BN_*H_*2;
    short* wt = (short*)w;                         w += (size_t)L_*LAYER_W*2;
    float* Epack = (float*)w;                                               // 4 KB

    k_front<<<KNN_BLKS + PREP_BLKS + 1, KFBLK, 0, stream>>>(x, ni, nd,
        miw, mow, uiw, uow, wt, ew, eb, mib, Epack);
    // per-node h0 / a(0) / c(0) via E-fusion
    k_prep0<<<BN_*H_/512, 512, 0, stream>>>(h, a, c0, x, ew, eb, Epack);
    // uniform layer loop, l = 0..3
    for (int l = 0; l < L_; ++l) {
        const short* c_rd = (l & 1) ? c1 : c0;
        short*       c_wr = (l & 1) ? c0 : c1;
        int do_ac = (l + 1 < L_);
        const short* wn = wt + (size_t)(do_ac ? (l+1) : l) * LAYER_W;
        const float* b1n = mib + (size_t)(do_ac ? (l+1) : l) * H_;
        k_layer<<<BN_/NPB_L, LBLK, 0, stream>>>(h, a, ni, nd,
            miw + (size_t)l*257*H_ + 256*H_,
            wt + (size_t)l*LAYER_W,
            mob + (size_t)l*H_, uib + (size_t)l*H_, uob + (size_t)l*H_,
            c_rd, c_wr, wn, b1n, do_ac,
            ow, ob, out);
    }
}